// Round 15
// baseline (102.958 us; speedup 1.0000x reference)
//
#include <hip/hip_runtime.h>

// AnnularDilatedKNN: B=4, N=4096, C=64, SAMPLE=16, DILATED_RATE=2, r^2=256.
// Round 18: round-17 with the ONE-LINE bug fix. r14 failed (absmax 127.9)
// from a transcription typo in chunk 2 of the dual-chunk loop:
//   d2c = (sqi + c2.w) - 2*dc   [c2.w = bitcast INDEX, not sqc!]
// round-16's correct line: d2c = (sqi + sqc) - 2*dc. Fixed; everything else
// byte-identical to round-17 (8 points/block, 512 thr, skeleton amortized).
//  - K1 verbatim round-16 (passed): cell=8 grid, NC=40, index in SP.w.
//  - K2: 2048 blocks, 8 waves/pt, mask[8][128], sids[128], part=t>>7,
//    ob=(beta&511)*128+rowi, launch_bounds(512,8) -> 32 waves/CU.
//  Hit test bit-identical: sq=(x*x+y*y)+z*z, dot=(xi*xj+yi*yj)+zi*zj,
//  d2=(sqi+sqj)-2*dot, contract off. Clamped dup rows harmless (mask OR
//  idempotent). Guarded loads only, no speculation.

#define BB 4
#define NN 4096
#define KK 16
#define PLANE (NN * KK)   // 65536
#define NC 40
#define NCELL2 (NC * NC)  // 1600

__device__ __forceinline__ int cell1d(float v)
{
    int c = (int)floorf((v + 160.0f) * 0.125f);
    c = c < 0 ? 0 : c;
    return c > (NC - 1) ? (NC - 1) : c;
}

// ---------- K1: per-batch 2D histogram -> scan -> scatter (1 block/batch) ----------
// 1024 threads; thread t owns points 4t..4t+3 of its batch.
__global__ __launch_bounds__(1024)
void preprocess(const float* __restrict__ xyz, float4* __restrict__ SP,
                int* __restrict__ CS)
{
#pragma clang fp contract(off)
    __shared__ int hist[NCELL2];

    const int b = blockIdx.x;
    const int t = threadIdx.x;
    const float4* xb4 = (const float4*)(xyz + (size_t)b * NN * 3);

    for (int c = t; c < NCELL2; c += 1024) hist[c] = 0;
    __syncthreads();

    // load 4 consecutive points (3 coalesced float4), keep in registers
    const float4 v0 = xb4[3 * t];
    const float4 v1 = xb4[3 * t + 1];
    const float4 v2 = xb4[3 * t + 2];
    const float px0 = v0.x, py0 = v0.y, pz0 = v0.z;
    const float px1 = v0.w, py1 = v1.x, pz1 = v1.y;
    const float px2 = v1.z, py2 = v1.w, pz2 = v2.x;
    const float px3 = v2.y, py3 = v2.z, pz3 = v2.w;
    const int c0 = cell1d(py0) * NC + cell1d(px0);
    const int c1 = cell1d(py1) * NC + cell1d(px1);
    const int c2 = cell1d(py2) * NC + cell1d(px2);
    const int c3 = cell1d(py3) * NC + cell1d(px3);
    atomicAdd(&hist[c0], 1);
    atomicAdd(&hist[c1], 1);
    atomicAdd(&hist[c2], 1);
    atomicAdd(&hist[c3], 1);
    __syncthreads();

    // wave 0 scans the 1600 cells (25 cells/lane, LDS re-read, no reg arrays)
    if (t < 64) {
        const int base = t * 25;                    // 64*25 = 1600 exactly
        int s = 0;
        for (int c = base; c < base + 25; ++c) s += hist[c];
        int x = s;
#pragma unroll
        for (int off = 1; off < 64; off <<= 1) {
            const int u = __shfl_up(x, off, 64);
            if (t >= off) x += u;
        }
        int acc = x - s;                            // exclusive prefix
        int* cs = CS + b * (NCELL2 + 1);
        for (int c = base; c < base + 25; ++c) {
            const int v = hist[c];
            cs[c]   = acc;
            hist[c] = acc;
            acc += v;
        }
        if (t == 0) cs[NCELL2] = NN;
    }
    __syncthreads();

    // scatter from registers; SP.w carries original index
    {
        int slot;
        slot = atomicAdd(&hist[c0], 1);
        SP[(b << 12) + slot] = make_float4(px0, py0, pz0, __int_as_float(4 * t + 0));
        slot = atomicAdd(&hist[c1], 1);
        SP[(b << 12) + slot] = make_float4(px1, py1, pz1, __int_as_float(4 * t + 1));
        slot = atomicAdd(&hist[c2], 1);
        SP[(b << 12) + slot] = make_float4(px2, py2, pz2, __int_as_float(4 * t + 2));
        slot = atomicAdd(&hist[c3], 1);
        SP[(b << 12) + slot] = make_float4(px3, py3, pz3, __int_as_float(4 * t + 3));
    }
}

// ---------- K2: fused grid ball query + gather ----------
// grid: 2048 blocks x 512 threads; block handles 8 consecutive points
// (ORIGINAL order), wave w queries point p0+w via 5 contiguous runs.
__global__ __launch_bounds__(512, 8)
void query_gather(const float* __restrict__ xyz, const float4* __restrict__ SP,
                  const int* __restrict__ CS, const float* __restrict__ feat,
                  float* __restrict__ out)
{
#pragma clang fp contract(off)
    __shared__ unsigned int mask[8][128];   // 4096-bit hit mask per point
    __shared__ int sids[8 * KK];

    const int beta = blockIdx.x;
    const int b    = beta >> 9;             // 512 blocks per batch
    const int p0   = (beta & 511) * 8;
    const int t    = threadIdx.x;
    const int lane = t & 63;
    const int wave = t >> 6;                // 0..7

    const float* xb   = xyz + (size_t)b * NN * 3;
    const float4* Sb  = SP + (b << 12);
    const int*    csb = CS + b * (NCELL2 + 1);

    // own point (original order): wave-uniform scalar loads, sq bit-identical
    const int   ip  = p0 + wave;
    const float pix = xb[3 * ip];
    const float piy = xb[3 * ip + 1];
    const float piz = xb[3 * ip + 2];
    const float sqi = (pix * pix + piy * piy) + piz * piz;

    // zero own mask (own-wave use only -> no barrier needed before query)
    unsigned int* m = mask[wave];
    m[2 * lane]     = 0u;
    m[2 * lane + 1] = 0u;

    // ---- query: 5 y-rows, bounds hoisted to named scalars, dual-chunk loop ----
    {
        const int cx = cell1d(pix), cy = cell1d(piy);
        const int xlo = cx > 1 ? cx - 2 : 0;
        const int xhi = cx < NC - 2 ? cx + 2 : NC - 1;
        const int y0 = (cy - 2) < 0 ? 0 : cy - 2;            // dup rows harmless (OR)
        const int y1 = (cy - 1) < 0 ? 0 : cy - 1;
        const int y3 = (cy + 1) > NC - 1 ? NC - 1 : cy + 1;
        const int y4 = (cy + 2) > NC - 1 ? NC - 1 : cy + 2;

        // all 10 bounds issued up-front, independent wave-uniform loads
        const int s0 = csb[y0 * NC + xlo], e0 = csb[y0 * NC + xhi + 1];
        const int s1 = csb[y1 * NC + xlo], e1 = csb[y1 * NC + xhi + 1];
        const int s2 = csb[cy * NC + xlo], e2 = csb[cy * NC + xhi + 1];
        const int s3 = csb[y3 * NC + xlo], e3 = csb[y3 * NC + xhi + 1];
        const int s4 = csb[y4 * NC + xlo], e4 = csb[y4 * NC + xhi + 1];

#pragma unroll
        for (int rr = 0; rr < 5; ++rr) {
            const int s = rr == 0 ? s0 : (rr == 1 ? s1 : (rr == 2 ? s2 : (rr == 3 ? s3 : s4)));
            const int e = rr == 0 ? e0 : (rr == 1 ? e1 : (rr == 2 ? e2 : (rr == 3 ? e3 : e4)));
            for (int v = s + lane; v < e; v += 128) {         // 2 chunks/iter
                const float4 a = Sb[v];
                const int v2   = v + 64;
                const bool h2  = v2 < e;
                float4 c2;
                if (h2) c2 = Sb[v2];                          // guarded, no spec
                const float sqa = (a.x * a.x + a.y * a.y) + a.z * a.z;
                const float da  = (pix * a.x + piy * a.y) + piz * a.z;
                const float d2a = (sqi + sqa) - 2.0f * da;
                if (d2a < 256.0f) {
                    const int j = __float_as_int(a.w);
                    atomicOr(&m[j >> 5], 1u << (j & 31));
                }
                if (h2) {
                    const float sqc = (c2.x * c2.x + c2.y * c2.y) + c2.z * c2.z;
                    const float dc  = (pix * c2.x + piy * c2.y) + piz * c2.z;
                    const float d2c = (sqi + sqc) - 2.0f * dc;   // FIXED: sqc
                    if (d2c < 256.0f) {
                        const int j = __float_as_int(c2.w);
                        atomicOr(&m[j >> 5], 1u << (j & 31));
                    }
                }
            }
        }
    }

    // ---- rank extraction: lane l owns indices [64l, 64l+64) (own mask) ----
    {
        const unsigned int lo  = m[2 * lane];
        const unsigned int hiw = m[2 * lane + 1];
        const unsigned long long w = ((unsigned long long)hiw << 32) | lo;
        const int c = __popcll(w);
        int x = c;                                  // inclusive scan of counts
#pragma unroll
        for (int off = 1; off < 64; off <<= 1) {
            const int u = __shfl_up(x, off, 64);
            if (lane >= off) x += u;
        }
        const int cnt  = __shfl(x, 63, 64);         // total hits
        const int base = x - c;                     // hits before this lane

        int fj = 0x7fffffff;                        // global first hit
        if (w) fj = (lane << 6) + __builtin_ctzll(w);
        for (int off = 32; off; off >>= 1) {
            const int o = __shfl_xor(fj, off, 64);
            fj = fj < o ? fj : o;
        }

        int* row = sids + wave * KK;
        if (w && base <= 30 && base + c > 16) {     // lane covers ranks 16..30?
            unsigned long long ww = w;
            int r = base;
            while (ww) {
                if (r > 30) break;
                if (r >= 16) row[r - 15] = (lane << 6) + __builtin_ctzll(ww);
                ww &= ww - 1;
                ++r;
            }
        }
        const int hi = (cnt < 31 ? cnt : 31) - 16;
        if (lane < KK && (lane == 0 || lane > hi)) row[lane] = fj;
    }
    __syncthreads();

    // ---- gather: thread t -> output row (t&127), channel quarter (t>>7) ----
    const int rowi = t & 127;
    const int part = t >> 7;                        // 0..3, 16 channels each
    const int id   = sids[rowi];
    const int ob   = (beta & 511) * 128 + rowi;

    if (part == 0) {                                // dilated_xyz [B,3,N,K]
        float* o0 = out + (size_t)b * 3 * PLANE + ob;
        o0[0]         = xb[3 * id];
        o0[PLANE]     = xb[3 * id + 1];
        o0[2 * PLANE] = xb[3 * id + 2];
    }

    // dilated_feature [B,64,N,K], channels [16*part, 16*part+16)
    const float4* frow = reinterpret_cast<const float4*>(feat + ((size_t)(b << 12) + id) * 64) + part * 4;
    float* o1 = out + (size_t)BB * 3 * PLANE + (size_t)b * 64 * PLANE
                    + (size_t)(part * 16) * PLANE + ob;
#pragma unroll
    for (int q = 0; q < 4; ++q) {
        const float4 v = frow[q];
        float* oc = o1 + (size_t)(4 * q) * PLANE;
        oc[0]         = v.x;
        oc[PLANE]     = v.y;
        oc[2 * PLANE] = v.z;
        oc[3 * PLANE] = v.w;
    }
}

extern "C" void kernel_launch(void* const* d_in, const int* in_sizes, int n_in,
                              void* d_out, int out_size, void* d_ws, size_t ws_size,
                              hipStream_t stream) {
    const float* xyz  = (const float*)d_in[0];
    const float* feat = (const float*)d_in[1];
    float* out = (float*)d_out;

    char* ws = (char*)d_ws;
    float4* SP = (float4*)(ws);                // 16384*16 = 262144
    int*    CS = (int*)   (ws + 262144);       // 4*1601*4 = 25616 (total ~288 KB)

    preprocess  <<<BB,          1024, 0, stream>>>(xyz, SP, CS);
    query_gather<<<BB * NN / 8, 512,  0, stream>>>(xyz, SP, CS, feat, out);
}

// Round 16
// 102.220 us; speedup vs baseline: 1.0072x; 1.0072x over previous
//
#include <hip/hip_runtime.h>

// AnnularDilatedKNN: B=4, N=4096, C=64, SAMPLE=16, DILATED_RATE=2, r^2=256.
// Round 19 (FINAL CONFIG): byte-identical resubmit of round-16 -- the best
// harness-verified kernel (102.0us). Round-15's 8-pt/block variant was
// neutral-to-worse (103.0); reverting to the measured optimum.
//  Budget (measured across 16 rounds): fill 46us (harness poison, 76% HBM
//  peak, fixed) + ~17us launch overhead (fixed) + K1 ~5 + K2 ~34.
//  K2 attack scoreboard: occupancy+MLP +5; candidate cuts x0.69/x0.12
//  neutral; sorted order -5; sq/SI -5; 8-pt blocks -1; restructures crash.
//  Config: cell=8 2D grid (NC=40, 1600 cells), 4 pts/block, 256 thr,
//  launch_bounds(256,8) -> 32 waves/CU; per-row dual-chunk guarded loop;
//  index bitcast in SP.w; 4096-bit LDS mask + popcount rank recovery.
//  Hit test bit-identical: sq=(x*x+y*y)+z*z, dot=(xi*xj+yi*yj)+zi*zj,
//  d2=(sqi+sqj)-2*dot, contract off. Clamped dup rows harmless (mask OR
//  idempotent). Guarded loads only, no speculation.

#define BB 4
#define NN 4096
#define KK 16
#define PLANE (NN * KK)   // 65536
#define NC 40
#define NCELL2 (NC * NC)  // 1600

__device__ __forceinline__ int cell1d(float v)
{
    int c = (int)floorf((v + 160.0f) * 0.125f);
    c = c < 0 ? 0 : c;
    return c > (NC - 1) ? (NC - 1) : c;
}

// ---------- K1: per-batch 2D histogram -> scan -> scatter (1 block/batch) ----------
// 1024 threads; thread t owns points 4t..4t+3 of its batch.
__global__ __launch_bounds__(1024)
void preprocess(const float* __restrict__ xyz, float4* __restrict__ SP,
                int* __restrict__ CS)
{
#pragma clang fp contract(off)
    __shared__ int hist[NCELL2];

    const int b = blockIdx.x;
    const int t = threadIdx.x;
    const float4* xb4 = (const float4*)(xyz + (size_t)b * NN * 3);

    for (int c = t; c < NCELL2; c += 1024) hist[c] = 0;
    __syncthreads();

    // load 4 consecutive points (3 coalesced float4), keep in registers
    const float4 v0 = xb4[3 * t];
    const float4 v1 = xb4[3 * t + 1];
    const float4 v2 = xb4[3 * t + 2];
    const float px0 = v0.x, py0 = v0.y, pz0 = v0.z;
    const float px1 = v0.w, py1 = v1.x, pz1 = v1.y;
    const float px2 = v1.z, py2 = v1.w, pz2 = v2.x;
    const float px3 = v2.y, py3 = v2.z, pz3 = v2.w;
    const int c0 = cell1d(py0) * NC + cell1d(px0);
    const int c1 = cell1d(py1) * NC + cell1d(px1);
    const int c2 = cell1d(py2) * NC + cell1d(px2);
    const int c3 = cell1d(py3) * NC + cell1d(px3);
    atomicAdd(&hist[c0], 1);
    atomicAdd(&hist[c1], 1);
    atomicAdd(&hist[c2], 1);
    atomicAdd(&hist[c3], 1);
    __syncthreads();

    // wave 0 scans the 1600 cells (25 cells/lane, LDS re-read, no reg arrays)
    if (t < 64) {
        const int base = t * 25;                    // 64*25 = 1600 exactly
        int s = 0;
        for (int c = base; c < base + 25; ++c) s += hist[c];
        int x = s;
#pragma unroll
        for (int off = 1; off < 64; off <<= 1) {
            const int u = __shfl_up(x, off, 64);
            if (t >= off) x += u;
        }
        int acc = x - s;                            // exclusive prefix
        int* cs = CS + b * (NCELL2 + 1);
        for (int c = base; c < base + 25; ++c) {
            const int v = hist[c];
            cs[c]   = acc;
            hist[c] = acc;
            acc += v;
        }
        if (t == 0) cs[NCELL2] = NN;
    }
    __syncthreads();

    // scatter from registers; SP.w carries original index
    {
        int slot;
        slot = atomicAdd(&hist[c0], 1);
        SP[(b << 12) + slot] = make_float4(px0, py0, pz0, __int_as_float(4 * t + 0));
        slot = atomicAdd(&hist[c1], 1);
        SP[(b << 12) + slot] = make_float4(px1, py1, pz1, __int_as_float(4 * t + 1));
        slot = atomicAdd(&hist[c2], 1);
        SP[(b << 12) + slot] = make_float4(px2, py2, pz2, __int_as_float(4 * t + 2));
        slot = atomicAdd(&hist[c3], 1);
        SP[(b << 12) + slot] = make_float4(px3, py3, pz3, __int_as_float(4 * t + 3));
    }
}

// ---------- K2: fused grid ball query + gather ----------
// grid: 4096 blocks x 256 threads; block handles 4 consecutive points
// (ORIGINAL order), wave w queries point p0+w via 5 contiguous runs.
__global__ __launch_bounds__(256, 8)
void query_gather(const float* __restrict__ xyz, const float4* __restrict__ SP,
                  const int* __restrict__ CS, const float* __restrict__ feat,
                  float* __restrict__ out)
{
#pragma clang fp contract(off)
    __shared__ unsigned int mask[4][128];   // 4096-bit hit mask per point
    __shared__ int sids[4 * KK];

    const int beta = blockIdx.x;
    const int b    = beta >> 10;
    const int p0   = (beta & 1023) * 4;
    const int t    = threadIdx.x;
    const int lane = t & 63;
    const int wave = t >> 6;

    const float* xb   = xyz + (size_t)b * NN * 3;
    const float4* Sb  = SP + (b << 12);
    const int*    csb = CS + b * (NCELL2 + 1);

    // own point (original order): wave-uniform scalar loads, sq bit-identical
    const int   ip  = p0 + wave;
    const float pix = xb[3 * ip];
    const float piy = xb[3 * ip + 1];
    const float piz = xb[3 * ip + 2];
    const float sqi = (pix * pix + piy * piy) + piz * piz;

    // zero own mask (own-wave use only -> no barrier needed before query)
    unsigned int* m = mask[wave];
    m[2 * lane]     = 0u;
    m[2 * lane + 1] = 0u;

    // ---- query: 5 y-rows, bounds hoisted to named scalars, dual-chunk loop ----
    {
        const int cx = cell1d(pix), cy = cell1d(piy);
        const int xlo = cx > 1 ? cx - 2 : 0;
        const int xhi = cx < NC - 2 ? cx + 2 : NC - 1;
        const int y0 = (cy - 2) < 0 ? 0 : cy - 2;            // dup rows harmless (OR)
        const int y1 = (cy - 1) < 0 ? 0 : cy - 1;
        const int y3 = (cy + 1) > NC - 1 ? NC - 1 : cy + 1;
        const int y4 = (cy + 2) > NC - 1 ? NC - 1 : cy + 2;

        // all 10 bounds issued up-front, independent wave-uniform loads
        const int s0 = csb[y0 * NC + xlo], e0 = csb[y0 * NC + xhi + 1];
        const int s1 = csb[y1 * NC + xlo], e1 = csb[y1 * NC + xhi + 1];
        const int s2 = csb[cy * NC + xlo], e2 = csb[cy * NC + xhi + 1];
        const int s3 = csb[y3 * NC + xlo], e3 = csb[y3 * NC + xhi + 1];
        const int s4 = csb[y4 * NC + xlo], e4 = csb[y4 * NC + xhi + 1];

#pragma unroll
        for (int rr = 0; rr < 5; ++rr) {
            const int s = rr == 0 ? s0 : (rr == 1 ? s1 : (rr == 2 ? s2 : (rr == 3 ? s3 : s4)));
            const int e = rr == 0 ? e0 : (rr == 1 ? e1 : (rr == 2 ? e2 : (rr == 3 ? e3 : e4)));
            for (int v = s + lane; v < e; v += 128) {         // 2 chunks/iter
                const float4 a = Sb[v];
                const int v2   = v + 64;
                const bool h2  = v2 < e;
                float4 c2;
                if (h2) c2 = Sb[v2];                          // guarded, no spec
                const float sqa = (a.x * a.x + a.y * a.y) + a.z * a.z;
                const float da  = (pix * a.x + piy * a.y) + piz * a.z;
                const float d2a = (sqi + sqa) - 2.0f * da;
                if (d2a < 256.0f) {
                    const int j = __float_as_int(a.w);
                    atomicOr(&m[j >> 5], 1u << (j & 31));
                }
                if (h2) {
                    const float sqc = (c2.x * c2.x + c2.y * c2.y) + c2.z * c2.z;
                    const float dc  = (pix * c2.x + piy * c2.y) + piz * c2.z;
                    const float d2c = (sqi + sqc) - 2.0f * dc;
                    if (d2c < 256.0f) {
                        const int j = __float_as_int(c2.w);
                        atomicOr(&m[j >> 5], 1u << (j & 31));
                    }
                }
            }
        }
    }

    // ---- rank extraction: lane l owns indices [64l, 64l+64) (own mask) ----
    {
        const unsigned int lo  = m[2 * lane];
        const unsigned int hiw = m[2 * lane + 1];
        const unsigned long long w = ((unsigned long long)hiw << 32) | lo;
        const int c = __popcll(w);
        int x = c;                                  // inclusive scan of counts
#pragma unroll
        for (int off = 1; off < 64; off <<= 1) {
            const int u = __shfl_up(x, off, 64);
            if (lane >= off) x += u;
        }
        const int cnt  = __shfl(x, 63, 64);         // total hits
        const int base = x - c;                     // hits before this lane

        int fj = 0x7fffffff;                        // global first hit
        if (w) fj = (lane << 6) + __builtin_ctzll(w);
        for (int off = 32; off; off >>= 1) {
            const int o = __shfl_xor(fj, off, 64);
            fj = fj < o ? fj : o;
        }

        int* row = sids + wave * KK;
        if (w && base <= 30 && base + c > 16) {     // lane covers ranks 16..30?
            unsigned long long ww = w;
            int r = base;
            while (ww) {
                if (r > 30) break;
                if (r >= 16) row[r - 15] = (lane << 6) + __builtin_ctzll(ww);
                ww &= ww - 1;
                ++r;
            }
        }
        const int hi = (cnt < 31 ? cnt : 31) - 16;
        if (lane < KK && (lane == 0 || lane > hi)) row[lane] = fj;
    }
    __syncthreads();

    // ---- gather: thread t -> output row (t&63), channel quarter (t>>6) ----
    const int rowi = t & 63;
    const int part = t >> 6;
    const int id   = sids[rowi];
    const int ob   = (beta & 1023) * 64 + rowi;

    if (part == 0) {                                // dilated_xyz [B,3,N,K]
        float* o0 = out + (size_t)b * 3 * PLANE + ob;
        o0[0]         = xb[3 * id];
        o0[PLANE]     = xb[3 * id + 1];
        o0[2 * PLANE] = xb[3 * id + 2];
    }

    // dilated_feature [B,64,N,K], channels [16*part, 16*part+16)
    const float4* frow = reinterpret_cast<const float4*>(feat + ((size_t)(b << 12) + id) * 64) + part * 4;
    float* o1 = out + (size_t)BB * 3 * PLANE + (size_t)b * 64 * PLANE
                    + (size_t)(part * 16) * PLANE + ob;
#pragma unroll
    for (int q = 0; q < 4; ++q) {
        const float4 v = frow[q];
        float* oc = o1 + (size_t)(4 * q) * PLANE;
        oc[0]         = v.x;
        oc[PLANE]     = v.y;
        oc[2 * PLANE] = v.z;
        oc[3 * PLANE] = v.w;
    }
}

extern "C" void kernel_launch(void* const* d_in, const int* in_sizes, int n_in,
                              void* d_out, int out_size, void* d_ws, size_t ws_size,
                              hipStream_t stream) {
    const float* xyz  = (const float*)d_in[0];
    const float* feat = (const float*)d_in[1];
    float* out = (float*)d_out;

    char* ws = (char*)d_ws;
    float4* SP = (float4*)(ws);                // 16384*16 = 262144
    int*    CS = (int*)   (ws + 262144);       // 4*1601*4 = 25616 (total ~288 KB)

    preprocess  <<<BB,          1024, 0, stream>>>(xyz, SP, CS);
    query_gather<<<BB * NN / 4, 256,  0, stream>>>(xyz, SP, CS, feat, out);
}